// Round 1
// baseline (222.255 us; speedup 1.0000x reference)
//
#include <hip/hip_runtime.h>
#include <float.h>

// Problem constants (from reference): B=64, Q=256 proposals, G=64 max GT, C=768 (unused).
#define QN 256
#define GN 64

// One workgroup (one 64-lane wave) solves one batch's rectangular Hungarian
// assignment (rows = GT, nb <= 64; cols = proposals, 256) exactly as the
// reference's Jonker-Volgenant implementation, with the per-column relaxation
// and argmin vectorized across the 64 lanes (4 columns per lane).
__global__ __launch_bounds__(64) void matcher_kernel(
    const float* __restrict__ gious,   // [B, Q, G]
    const int*   __restrict__ nactual, // [B] (int64 in reference -> int32 here)
    float*       __restrict__ out,     // [2*B*Q]: [0,BQ) = per_prop_gt_inds, [BQ,2BQ) = mask
    int B)
{
    const int b   = blockIdx.x;
    const int tid = threadIdx.x;

    __shared__ float  costT[GN][QN + 1];   // cost[g][q] = -2*gious[b][q][g]; +1 pad: bank-conflict-free
    __shared__ double sh_short[QN];
    __shared__ double sh_v[QN];
    __shared__ double sh_u[GN];
    __shared__ int    sh_path[QN];
    __shared__ int    sh_row4col[QN];
    __shared__ int    sh_col4row[GN];
    __shared__ unsigned char sh_SC[QN];
    __shared__ unsigned char sh_SR[GN];

    int nb = nactual[b];
    if (nb < 0)  nb = 0;
    if (nb > GN) nb = GN;

    // ---- stage transposed cost into LDS (coalesced global, conflict-free LDS) ----
    const float* gb = gious + (size_t)b * QN * GN;
    for (int f = tid; f < QN * GN; f += 64) {
        int q = f >> 6;   // proposal
        int g = f & 63;   // gt
        costT[g][q] = -2.0f * gb[f];
    }
    // ---- init ----
    for (int k = 0; k < 4; ++k) {
        int j = tid + 64 * k;
        sh_v[j] = 0.0;
        sh_row4col[j] = -1;
    }
    sh_u[tid] = 0.0;
    sh_col4row[tid] = -1;
    __syncthreads();

    for (int cur = 0; cur < nb; ++cur) {
        // per-row reset
        for (int k = 0; k < 4; ++k) {
            int j = tid + 64 * k;
            sh_short[j] = DBL_MAX;
            sh_SC[j] = 0;
            sh_path[j] = -1;
        }
        sh_SR[tid] = 0;
        __syncthreads();

        double min_val = 0.0;
        int i    = cur;
        int sink = -1;
        while (sink < 0) {
            if (tid == 0) sh_SR[i] = 1;
            double ui = sh_u[i];
            // relax all non-SC columns (same op order as numpy: ((min+c)-u)-v)
            for (int k = 0; k < 4; ++k) {
                int j = tid + 64 * k;
                if (!sh_SC[j]) {
                    double r = min_val + (double)costT[i][j] - ui - sh_v[j];
                    if (r < sh_short[j]) { sh_short[j] = r; sh_path[j] = i; }
                }
            }
            // argmin over remaining (tie -> smallest column index, matches np.argmin)
            double bestv = DBL_MAX;
            int    bestj = QN;
            for (int k = 0; k < 4; ++k) {
                int j = tid + 64 * k;
                if (!sh_SC[j]) {
                    double s = sh_short[j];
                    if (s < bestv || (s == bestv && j < bestj)) { bestv = s; bestj = j; }
                }
            }
            for (int off = 1; off < 64; off <<= 1) {
                double ov = __shfl_xor(bestv, off, 64);
                int    oj = __shfl_xor(bestj, off, 64);
                if (ov < bestv || (ov == bestv && oj < bestj)) { bestv = ov; bestj = oj; }
            }
            min_val = bestv;
            int jstar = bestj;
            int r4 = sh_row4col[jstar];
            if (r4 < 0) sink = jstar;
            else        i = r4;
            if (tid == 0) sh_SC[jstar] = 1;
            __syncthreads();
        }

        // ---- dual variable update (reference order: duals first, then augment) ----
        // rows: u[cur] += min_val; u[i in SR, i != cur] += min_val - shortest[col4row[i]]
        if (tid == cur) {
            sh_u[tid] += min_val;
        } else if (sh_SR[tid]) {
            sh_u[tid] += min_val - sh_short[sh_col4row[tid]];
        }
        // cols: v[j in SC] -= min_val - shortest[j]
        for (int k = 0; k < 4; ++k) {
            int j = tid + 64 * k;
            if (sh_SC[j]) sh_v[j] -= min_val - sh_short[j];
        }
        __syncthreads();

        // ---- augment along alternating path (serial, lane 0) ----
        if (tid == 0) {
            int j = sink;
            while (true) {
                int pi = sh_path[j];
                sh_row4col[j] = pi;
                int jn = sh_col4row[pi];
                sh_col4row[pi] = j;
                j = jn;
                if (pi == cur) break;
            }
        }
        __syncthreads();
    }

    // ---- write outputs (covers every element -> poison-safe) ----
    const size_t BQ = (size_t)B * QN;
    for (int k = 0; k < 4; ++k) {
        int j = tid + 64 * k;
        int g = sh_row4col[j];
        out[(size_t)b * QN + j]      = (g >= 0) ? (float)g : 0.0f;
        out[BQ + (size_t)b * QN + j] = (g >= 0) ? 1.0f : 0.0f;
    }
}

extern "C" void kernel_launch(void* const* d_in, const int* in_sizes, int n_in,
                              void* d_out, int out_size, void* d_ws, size_t ws_size,
                              hipStream_t stream) {
    // inputs: 0 last_sem_cls_scores (unused), 1 gious [B,Q,G], 2 positive_map (unused),
    //         3 sem_cls_label (unused), 4 nactual_gt [B]
    const float* gious   = (const float*)d_in[1];
    const int*   nactual = (const int*)d_in[4];
    float*       out     = (float*)d_out;
    const int B = in_sizes[4];

    matcher_kernel<<<B, 64, 0, stream>>>(gious, nactual, out, B);
}

// Round 2
// 163.919 us; speedup vs baseline: 1.3559x; 1.3559x over previous
//
#include <hip/hip_runtime.h>
#include <float.h>
#include <limits.h>

// Problem constants: B=64, Q=256 proposals, G=64 max GT, C=768 (unused).
#define QN 256
#define GN 64

__device__ __forceinline__ double mkdbl(int lo, int hi) { return __hiloint2double(hi, lo); }

// Exact 64-lane argmin on (double value, int index) pairs, tie -> smallest index
// (matches np.argmin over columns in ascending order). Pure-VALU DPP reduction:
// row_shr 1/2/4/8 then row_bcast15/31; result lands in lane 63, broadcast back.
__device__ __forceinline__ void wave_argmin(double &val, int &idx) {
#define AM_STEP(CTRL, RMASK)                                                   \
  {                                                                            \
    int lo  = __double2loint(val), hi = __double2hiint(val);                   \
    int nlo = __builtin_amdgcn_update_dpp(lo,  lo,  CTRL, RMASK, 0xf, false);  \
    int nhi = __builtin_amdgcn_update_dpp(hi,  hi,  CTRL, RMASK, 0xf, false);  \
    int nix = __builtin_amdgcn_update_dpp(idx, idx, CTRL, RMASK, 0xf, false);  \
    double nv = mkdbl(nlo, nhi);                                               \
    bool take = (nv < val) || (nv == val && nix < idx);                        \
    val = take ? nv : val;                                                     \
    idx = take ? nix : idx;                                                    \
  }
  AM_STEP(0x111, 0xf)  // row_shr:1
  AM_STEP(0x112, 0xf)  // row_shr:2
  AM_STEP(0x114, 0xf)  // row_shr:4
  AM_STEP(0x118, 0xf)  // row_shr:8  -> lane15 of each 16-row has row min
  AM_STEP(0x142, 0xa)  // row_bcast15 into rows 1,3
  AM_STEP(0x143, 0xc)  // row_bcast31 into rows 2,3 -> lane 63 has global min
#undef AM_STEP
  int lo = __builtin_amdgcn_readlane(__double2loint(val), 63);
  int hi = __builtin_amdgcn_readlane(__double2hiint(val), 63);
  idx    = __builtin_amdgcn_readlane(idx, 63);
  val    = mkdbl(lo, hi);
}

// One 64-lane wave per batch. Lane t owns columns 4t..4t+3 (shortest/v/path/SC/
// row4col in registers) and row t (u/col4row/SR in registers). Only LDS in the
// hot loop: one conflict-free ds_read_b128 of the cost row. Exact JV semantics
// (double, numpy op order) so assignments match the reference bitwise.
__global__ __launch_bounds__(64) void matcher_kernel(
    const float* __restrict__ gious,   // [B, Q, G]
    const int*   __restrict__ nactual, // [B]
    float*       __restrict__ out,     // [2*B*Q]
    int B)
{
  const int b = blockIdx.x;
  const int t = threadIdx.x;

  __shared__ float costQ[QN][GN + 1];  // [q][g], pad -> staging conflict-free
  __shared__ float costT[GN][QN];      // [g][q], hot-loop layout

  int nb = nactual[b];
  nb = nb < 0 ? 0 : (nb > GN ? GN : nb);

  // ---- stage 1: coalesced float4 global reads -> costQ[q][g] (2-way LDS writes, free)
  const float4* gb4 = (const float4*)(gious + (size_t)b * QN * GN);
  {
    const int q_sub = t >> 4;        // which of 4 q's this lane covers per iter
    const int g0    = 4 * (t & 15);  // 4 consecutive g
#pragma unroll 4
    for (int it = 0; it < 64; ++it) {
      float4 x = gb4[it * 64 + t];
      int q = it * 4 + q_sub;
      costQ[q][g0 + 0] = -2.0f * x.x;
      costQ[q][g0 + 1] = -2.0f * x.y;
      costQ[q][g0 + 2] = -2.0f * x.z;
      costQ[q][g0 + 3] = -2.0f * x.w;
    }
  }
  __syncthreads();
  // ---- stage 2: transpose -> costT[g][q] (both sides 2-way, free)
#pragma unroll
  for (int qq = 0; qq < 4; ++qq) {
    int q = qq * 64 + t;
#pragma unroll 8
    for (int g = 0; g < GN; ++g) costT[g][q] = costQ[q][g];
  }
  __syncthreads();

  // ---- persistent per-lane state ----
  double v0 = 0, v1 = 0, v2 = 0, v3 = 0;          // v[4t..4t+3]
  int r4c0 = -1, r4c1 = -1, r4c2 = -1, r4c3 = -1; // row4col[4t..4t+3]
  double u = 0.0;                                  // u[t]
  int col4row = -1;                                // col4row[t]

  const float* costRow0 = &costT[0][0];

  for (int cur = 0; cur < nb; ++cur) {
    double s0 = DBL_MAX, s1 = DBL_MAX, s2 = DBL_MAX, s3 = DBL_MAX; // shortest
    int p0 = -1, p1 = -1, p2 = -1, p3 = -1;                         // path
    int scm = 0;  // SC bits for my 4 columns
    int sr  = 0;  // SR flag for my row
    double min_val = 0.0;
    int i = cur;
    int sink = -1;

    while (sink < 0) {
      // cost row i, my 4 columns (issue load first; i is wave-uniform)
      float4 c4 = *(const float4*)(costRow0 + i * QN + 4 * t);
      if (t == i) sr = 1;
      // u[i] broadcast
      double u_i = mkdbl(__builtin_amdgcn_readlane(__double2loint(u), i),
                         __builtin_amdgcn_readlane(__double2hiint(u), i));
      // relax (numpy op order: ((min_val + c) - u_i) - v)
      double r;
      r = ((min_val + (double)c4.x) - u_i) - v0; if (!(scm & 1) && r < s0) { s0 = r; p0 = i; }
      r = ((min_val + (double)c4.y) - u_i) - v1; if (!(scm & 2) && r < s1) { s1 = r; p1 = i; }
      r = ((min_val + (double)c4.z) - u_i) - v2; if (!(scm & 4) && r < s2) { s2 = r; p2 = i; }
      r = ((min_val + (double)c4.w) - u_i) - v3; if (!(scm & 8) && r < s3) { s3 = r; p3 = i; }
      // local argmin over my non-SC slots (ascending index -> np tie-break)
      double bv = (scm & 1) ? DBL_MAX : s0;
      int    bj = (scm & 1) ? INT_MAX : 4 * t + 0;
      if (!(scm & 2) && s1 < bv) { bv = s1; bj = 4 * t + 1; }
      if (!(scm & 4) && s2 < bv) { bv = s2; bj = 4 * t + 2; }
      if (!(scm & 8) && s3 < bv) { bv = s3; bj = 4 * t + 3; }
      // global argmin (exact pair compare)
      wave_argmin(bv, bj);
      min_val = bv;
      int jstar = bj;
      int jo = jstar >> 2, sl = jstar & 3;
      // r4 = row4col[jstar]
      int rsel = (sl == 0) ? r4c0 : (sl == 1) ? r4c1 : (sl == 2) ? r4c2 : r4c3;
      int r4 = __builtin_amdgcn_readlane(rsel, jo);
      // SC[jstar] = 1
      if (t == jo) scm |= (1 << sl);
      if (r4 < 0) sink = jstar;
      else        i = r4;
    }

    // ---- dual update (reference order; uses final shortest, pre-augment col4row)
    {
      int c  = col4row < 0 ? 0 : col4row;
      int ow = (c >> 2) & 63, sl2 = c & 3;
      double g0 = __shfl(s0, ow, 64);
      double g1 = __shfl(s1, ow, 64);
      double g2 = __shfl(s2, ow, 64);
      double g3 = __shfl(s3, ow, 64);
      double s_c = (sl2 == 0) ? g0 : (sl2 == 1) ? g1 : (sl2 == 2) ? g2 : g3;
      if (t == cur)  u += min_val;
      else if (sr)   u += min_val - s_c;
      if (scm & 1) v0 -= min_val - s0;
      if (scm & 2) v1 -= min_val - s1;
      if (scm & 4) v2 -= min_val - s2;
      if (scm & 8) v3 -= min_val - s3;
    }

    // ---- augment along alternating path (uniform walk, lockstep)
    {
      int j = sink;
      while (true) {
        int jo = j >> 2, sl = j & 3;
        int pv = (sl == 0) ? p0 : (sl == 1) ? p1 : (sl == 2) ? p2 : p3;
        int pi = __builtin_amdgcn_readlane(pv, jo);
        if (t == jo) {
          if      (sl == 0) r4c0 = pi;
          else if (sl == 1) r4c1 = pi;
          else if (sl == 2) r4c2 = pi;
          else              r4c3 = pi;
        }
        int jn = __builtin_amdgcn_readlane(col4row, pi);
        if (t == pi) col4row = j;
        j = jn;
        if (pi == cur) break;
      }
    }
  }

  // ---- outputs (every element written -> poison-safe) ----
  {
    const size_t BQ = (size_t)B * QN;
    int base = b * QN + 4 * t;
    float4 inds = make_float4(r4c0 >= 0 ? (float)r4c0 : 0.0f,
                              r4c1 >= 0 ? (float)r4c1 : 0.0f,
                              r4c2 >= 0 ? (float)r4c2 : 0.0f,
                              r4c3 >= 0 ? (float)r4c3 : 0.0f);
    float4 mask = make_float4(r4c0 >= 0 ? 1.0f : 0.0f,
                              r4c1 >= 0 ? 1.0f : 0.0f,
                              r4c2 >= 0 ? 1.0f : 0.0f,
                              r4c3 >= 0 ? 1.0f : 0.0f);
    *(float4*)&out[base]      = inds;
    *(float4*)&out[BQ + base] = mask;
  }
}

extern "C" void kernel_launch(void* const* d_in, const int* in_sizes, int n_in,
                              void* d_out, int out_size, void* d_ws, size_t ws_size,
                              hipStream_t stream) {
  // inputs: 0 last_sem_cls_scores (unused), 1 gious [B,Q,G], 2 positive_map (unused),
  //         3 sem_cls_label (unused), 4 nactual_gt [B]
  const float* gious   = (const float*)d_in[1];
  const int*   nactual = (const int*)d_in[4];
  float*       out     = (float*)d_out;
  const int B = in_sizes[4];

  matcher_kernel<<<B, 64, 0, stream>>>(gious, nactual, out, B);
}